// Round 11
// baseline (224.218 us; speedup 1.0000x reference)
//
#include <hip/hip_runtime.h>
#include <hip/hip_bf16.h>

typedef __bf16 bf16;
typedef __bf16 bf16x8 __attribute__((ext_vector_type(8)));
typedef int i32x4 __attribute__((ext_vector_type(4)));
typedef signed char scx8 __attribute__((ext_vector_type(8)));

__device__ __forceinline__ void gload_lds16(const void* g, void* l) {
  __builtin_amdgcn_global_load_lds(
      (const __attribute__((address_space(1))) void*)g,
      (__attribute__((address_space(3))) void*)l, 16, 0, 0);
}

// ---------------------------------------------------------------------------
// i8 GEMM core: C_i32 = A[M,K]i8 @ B[N,K]i8^T.  128x128 tile, BK=64 (64B
// rows), 256 thr = 4 waves (2x2), 4x4 mfma_i32_16x16x64_i8 per wave.
// r11 change: DOUBLE-buffered LDS (2 x 16KB = 32KB) -> 5 blocks/CU (20
// waves, ~62% occupancy; was 3 blocks at 48KB).  Depth-1 staging: stage(t+1)
// issued after iter-t ds_reads; its buffer's readers all completed before
// barrier(t) (reads lgkm-waited before MFMA issue, MFMA before barrier).
// Per-iter vmcnt(0) drains loads issued a FULL iteration earlier (~2000 cyc
// head start vs ~300 cyc L2 latency) -> near-zero wait; 5-way block TLP
// covers the remainder.  0-conflict XOR swizzle unchanged.
// EPI=1: sigmoid((sA[m]*sB[n])*acc) -> bf16.   EPI=0: (sB[n]/127)*acc +
// bias[n] -> f32 (A-scale fixed 1/127).
// ---------------------------------------------------------------------------
template <int EPI>
__global__ __launch_bounds__(256, 5) void gemm_i8(
    const signed char* __restrict__ A, const signed char* __restrict__ Bw,
    const float* __restrict__ sA, const float* __restrict__ sB,
    const float* __restrict__ bias, void* __restrict__ C, int M, int N, int K) {
  __shared__ __align__(16) char smem[32768];  // buf b at b*16K: A 8K, B 8K
  const int tid = threadIdx.x;
  const int lane = tid & 63;
  const int wave = tid >> 6;

  const int nb = N >> 7;
  const int nwg = gridDim.x;
  const int q8 = nwg >> 3;  // grids divisible by 8
  const int tile = ((int)blockIdx.x & 7) * q8 + ((int)blockIdx.x >> 3);
  const int m0 = (tile / nb) << 7;
  const int n0 = (tile % nb) << 7;

  const int wm = (wave >> 1) << 6;
  const int wn = (wave & 1) << 6;

  i32x4 acc[4][4] = {};

  // ---- staging constants (hoisted): 4 chunks/thread, ptrs advance +64/call --
  const int r_in = lane >> 2;                      // row within 16-row chunk
  const int swz = ((lane >> 3) & 3) << 4;          // bits1-2 of r_in
  const int scolb = ((lane & 3) << 4) ^ swz;       // source byte col
  const signed char* gA0 = A + (size_t)(m0 + (wave << 4) + r_in) * K + scolb;
  const signed char* gA1 = gA0 + ((size_t)K << 6);   // +64 rows
  const signed char* gB0 = Bw + (size_t)(n0 + (wave << 4) + r_in) * K + scolb;
  const signed char* gB1 = gB0 + ((size_t)K << 6);
  const int ldsoff = (wave << 10) + (lane << 4);     // A-chunk dest in buf

  auto stage = [&](int buf) {
    char* b = smem + buf * 16384 + ldsoff;
    gload_lds16(gA0, b);
    gload_lds16(gA1, b + 4096);
    gload_lds16(gB0, b + 8192);
    gload_lds16(gB1, b + 12288);
    gA0 += 64; gA1 += 64; gB0 += 64; gB1 += 64;
  };

  const int lrow = lane & 15;
  const int koff = ((lane >> 4) << 4) ^ (((lrow >> 1) & 3) << 4);

  const int nt = K >> 6;  // 16 for K=1024

  stage(0);

  for (int t = 0; t < nt; ++t) {
    const int buf = t & 1;
    asm volatile("s_waitcnt vmcnt(0)" ::: "memory");  // stage(t) landed
    __builtin_amdgcn_s_barrier();
    __builtin_amdgcn_sched_barrier(0);  // keep ds_reads below the barrier

    i32x4 af[4], bg[4];
    const char* base = smem + buf * 16384;
#pragma unroll
    for (int i = 0; i < 4; ++i) {
      af[i] = *(const i32x4*)(base + (wm + (i << 4) + lrow) * 64 + koff);
      bg[i] = *(const i32x4*)(base + 8192 + (wn + (i << 4) + lrow) * 64 + koff);
    }

    if (t + 1 < nt) stage(buf ^ 1);  // target's readers done before barrier(t)

    // compiler emits counted lgkmcnt per MFMA dep
#pragma unroll
    for (int i = 0; i < 4; ++i)
#pragma unroll
      for (int j = 0; j < 4; ++j)
        acc[i][j] =
            __builtin_amdgcn_mfma_i32_16x16x64_i8(af[i], bg[j], acc[i][j], 0, 0, 0);
  }

  // epilogue: C/D layout col=lane&15, row=(lane>>4)*4+reg
  const int col0 = n0 + wn + lrow;
  const int rowb = m0 + wm + ((lane >> 4) << 2);
  float sb[4], bi[4];
#pragma unroll
  for (int j = 0; j < 4; ++j) {
    sb[j] = sB[col0 + (j << 4)];
    if (EPI == 0) bi[j] = bias[col0 + (j << 4)];
  }
#pragma unroll
  for (int i = 0; i < 4; ++i)
#pragma unroll
    for (int r = 0; r < 4; ++r) {
      const int row = rowb + (i << 4) + r;
      const float sa = (EPI == 1) ? sA[row] : (1.0f / 127.0f);
#pragma unroll
      for (int j = 0; j < 4; ++j) {
        const size_t idx = (size_t)row * N + (col0 + (j << 4));
        const float v = (float)acc[i][j][r] * (sa * sb[j]);
        if (EPI == 1) {
          ((bf16*)C)[idx] = (bf16)(1.0f / (1.0f + __expf(-v)));
        } else {
          ((float*)C)[idx] = v + bi[j];
        }
      }
    }
}

// ---------------------------------------------------------------------------
// Windowed Hamming attention.  One thread per (b,s,h).  Gate is folded into
// the output GEMM (W2 = Wo .* (emb1-emb0), bias = Wo @ emb0), so this emits
// raw o in [0,1] quantized to i8 with fixed scale 127.
// ---------------------------------------------------------------------------
__global__ __launch_bounds__(256) void rosa_attn(
    const bf16* __restrict__ qkv, signed char* __restrict__ Oq) {
  const int t = blockIdx.x * 256 + threadIdx.x;
  const int row = t >> 7;
  const int h = t & 127;
  const int sp = row & 4095;

  const bf16* qptr = qkv + (size_t)row * 3072 + h * 8;
  bf16x8 qv = *(const bf16x8*)qptr;
  float qb[8], qsum = 0.f;
#pragma unroll
  for (int c = 0; c < 8; ++c) {
    qb[c] = (float)qv[c];
    qsum += qb[c];
  }

  float oacc[8] = {};
  float wsum = 0.f;
  const int wmax = (sp + 1 < 8) ? (sp + 1) : 8;
  const float scale = 0.35355339059327373f;

  for (int d = 0; d < wmax; ++d) {
    const bf16* base = qkv + (size_t)(row - d) * 3072 + h * 8;
    bf16x8 kv = *(const bf16x8*)(base + 1024);
    bf16x8 vv = *(const bf16x8*)(base + 2048);
    float dot = 0.f, ksum = 0.f;
#pragma unroll
    for (int c = 0; c < 8; ++c) {
      const float kb = (float)kv[c];
      dot += qb[c] * kb;
      ksum += kb;
    }
    const float score = (8.0f + 2.0f * dot - qsum - ksum) * scale;
    const float w = __expf(score);
    wsum += w;
#pragma unroll
    for (int c = 0; c < 8; ++c) oacc[c] += w * (float)vv[c];
  }

  const float inv = 127.0f / wsum;
  scx8 outv;
#pragma unroll
  for (int c = 0; c < 8; ++c)
    outv[c] = (signed char)(int)(oacc[c] * inv + 0.5f);  // o in [0,1]
  *(scx8*)(Oq + (size_t)row * 1024 + h * 8) = outv;
}

// ---------------------------------------------------------------------------
// Per-row i8 quantization.  One block (256 thr) per 1024-elem row.
// ---------------------------------------------------------------------------
__global__ __launch_bounds__(256) void quant_all(
    const float* __restrict__ X, const float* __restrict__ Wq,
    const float* __restrict__ Wk, const float* __restrict__ Wv,
    const float* __restrict__ Wo, const float* __restrict__ emb0,
    const float* __restrict__ emb1, signed char* __restrict__ Xq,
    signed char* __restrict__ Wqkvq, signed char* __restrict__ W2q,
    float* __restrict__ sx, float* __restrict__ sw, float* __restrict__ sw2,
    float* __restrict__ bias) {
  __shared__ float redm[4], reds[4];
  const int b = blockIdx.x, tid = threadIdx.x;
  const float* srow;
  signed char* drow;
  float* sc;
  bool isW2 = false;
  int w2r = 0;
  if (b < 8192) {
    srow = X + (size_t)b * 1024; drow = Xq + (size_t)b * 1024; sc = sx + b;
  } else if (b < 11264) {
    const int r = b - 8192;
    const float* w = (r < 1024) ? Wq : (r < 2048 ? Wk : Wv);
    srow = w + (size_t)(r & 1023) * 1024;
    drow = Wqkvq + (size_t)r * 1024; sc = sw + r;
  } else {
    const int r = b - 11264; w2r = r;
    srow = Wo + (size_t)r * 1024; drow = W2q + (size_t)r * 1024; sc = sw2 + r;
    isW2 = true;
  }
  float4 v = ((const float4*)srow)[tid];
  float bsum = 0.f;
  if (isW2) {
    const float4 e1 = ((const float4*)emb1)[tid];
    const float4 e0 = ((const float4*)emb0)[tid];
    bsum = v.x * e0.x + v.y * e0.y + v.z * e0.z + v.w * e0.w;
    v.x *= (e1.x - e0.x); v.y *= (e1.y - e0.y);
    v.z *= (e1.z - e0.z); v.w *= (e1.w - e0.w);
  }
  float m = fmaxf(fmaxf(fabsf(v.x), fabsf(v.y)), fmaxf(fabsf(v.z), fabsf(v.w)));
#pragma unroll
  for (int off = 32; off; off >>= 1) m = fmaxf(m, __shfl_xor(m, off));
#pragma unroll
  for (int off = 32; off; off >>= 1) bsum += __shfl_xor(bsum, off);
  if ((tid & 63) == 0) { redm[tid >> 6] = m; reds[tid >> 6] = bsum; }
  __syncthreads();
  const float mx = fmaxf(fmaxf(redm[0], redm[1]), fmaxf(redm[2], redm[3]));
  const float inv = (mx > 0.f) ? 127.f / mx : 0.f;
  const int q0 = __float2int_rn(v.x * inv) & 255;
  const int q1 = __float2int_rn(v.y * inv) & 255;
  const int q2 = __float2int_rn(v.z * inv) & 255;
  const int q3 = __float2int_rn(v.w * inv) & 255;
  ((int*)drow)[tid] = q0 | (q1 << 8) | (q2 << 16) | (q3 << 24);
  if (tid == 0) {
    *sc = (mx > 0.f) ? mx / 127.f : 0.f;
    if (isW2) bias[w2r] = reds[0] + reds[1] + reds[2] + reds[3];
  }
}

// ---------------------------------------------------------------------------
extern "C" void kernel_launch(void* const* d_in, const int* in_sizes, int n_in,
                              void* d_out, int out_size, void* d_ws,
                              size_t ws_size, hipStream_t stream) {
  const float* X = (const float*)d_in[0];
  const float* Wq = (const float*)d_in[1];
  const float* Wk = (const float*)d_in[2];
  const float* Wv = (const float*)d_in[3];
  const float* Wo = (const float*)d_in[4];
  const float* emb0 = (const float*)d_in[5];
  const float* emb1 = (const float*)d_in[6];

  char* ws = (char*)d_ws;
  signed char* Xq    = (signed char*)(ws + 0);         // 8192*1024  (8 MB)
  signed char* Wqkvq = (signed char*)(ws + 8388608);   // 3072*1024  (3 MB)
  signed char* W2q   = (signed char*)(ws + 11534336);  // 1024*1024  (1 MB)
  float* sx   = (float*)(ws + 12582912);               // 8192 f32
  float* sw   = (float*)(ws + 12615680);               // 3072 f32
  float* sw2  = (float*)(ws + 12627968);               // 1024 f32
  float* bias = (float*)(ws + 12632064);               // 1024 f32
  bf16* QKVb  = (bf16*)(ws + 16777216);                // 8192*3072 bf16 (48 MB)
  signed char* Oq = (signed char*)(ws + 67108864);     // 8192*1024  (8 MB)
  float* out = (float*)d_out;

  // per-row i8 quantization of X, Wq|Wk|Wv, W2 (gate folded) + bias GEMV
  quant_all<<<12288, 256, 0, stream>>>(X, Wq, Wk, Wv, Wo, emb0, emb1, Xq,
                                       Wqkvq, W2q, sx, sw, sw2, bias);

  // fused QKV projection (i8 MFMA) + sigmoid -> bf16 (M=8192,N=3072,K=1024)
  gemm_i8<1><<<1536, 256, 0, stream>>>(Xq, Wqkvq, sx, sw, nullptr, QKVb, 8192,
                                       3072, 1024);

  // windowed attention -> raw o as i8 (scale 127)
  rosa_attn<<<4096, 256, 0, stream>>>(QKVb, Oq);

  // output projection (i8 MFMA) + bias -> f32 (M=8192,N=1024,K=1024)
  gemm_i8<0><<<512, 256, 0, stream>>>(Oq, W2q, nullptr, sw2, bias, out, 8192,
                                      1024, 1024);
}

// Round 12
// 102.330 us; speedup vs baseline: 2.1911x; 2.1911x over previous
//
#include <hip/hip_runtime.h>
#include <hip/hip_bf16.h>

typedef __bf16 bf16;
typedef __bf16 bf16x8 __attribute__((ext_vector_type(8)));
typedef int i32x4 __attribute__((ext_vector_type(4)));
typedef signed char scx8 __attribute__((ext_vector_type(8)));

__device__ __forceinline__ void gload_lds16(const void* g, void* l) {
  __builtin_amdgcn_global_load_lds(
      (const __attribute__((address_space(1))) void*)g,
      (__attribute__((address_space(3))) void*)l, 16, 0, 0);
}

// ---------------------------------------------------------------------------
// i8 GEMM core: C_i32 = A[M,K]i8 @ B[N,K]i8^T.  128x128 tile, BK=64 (64B
// rows), 256 thr = 4 waves (2x2), 4x4 mfma_i32_16x16x64_i8 per wave.
// Double-buffered LDS (2 x 16KB = 32KB).  __launch_bounds__(256,4): 4
// waves/SIMD -> VGPR cap 128 (kernel uses ~68, NO SPILL — r11's (256,5)
// capped VGPR at 48 and spilled acc to scratch, WRITE_SIZE 49->360MB).
// 4 blocks/CU.  Depth-1 staging: stage(t+1) issued after iter-t ds_reads
// (target buffer's readers completed before barrier(t)).  Per-iter vmcnt(0)
// drains loads issued a full iteration earlier.  0-conflict XOR swizzle.
// EPI=1: sigmoid((sA[m]*sB[n])*acc) -> bf16.   EPI=0: (sB[n]/127)*acc +
// bias[n] -> f32 (A-scale fixed 1/127).
// ---------------------------------------------------------------------------
template <int EPI>
__global__ __launch_bounds__(256, 4) void gemm_i8(
    const signed char* __restrict__ A, const signed char* __restrict__ Bw,
    const float* __restrict__ sA, const float* __restrict__ sB,
    const float* __restrict__ bias, void* __restrict__ C, int M, int N, int K) {
  __shared__ __align__(16) char smem[32768];  // buf b at b*16K: A 8K, B 8K
  const int tid = threadIdx.x;
  const int lane = tid & 63;
  const int wave = tid >> 6;

  const int nb = N >> 7;
  const int nwg = gridDim.x;
  const int q8 = nwg >> 3;  // grids divisible by 8
  const int tile = ((int)blockIdx.x & 7) * q8 + ((int)blockIdx.x >> 3);
  const int m0 = (tile / nb) << 7;
  const int n0 = (tile % nb) << 7;

  const int wm = (wave >> 1) << 6;
  const int wn = (wave & 1) << 6;

  i32x4 acc[4][4] = {};

  // ---- staging constants (hoisted): 4 chunks/thread, ptrs advance +64/call --
  const int r_in = lane >> 2;                      // row within 16-row chunk
  const int swz = ((lane >> 3) & 3) << 4;          // bits1-2 of r_in
  const int scolb = ((lane & 3) << 4) ^ swz;       // source byte col
  const signed char* gA0 = A + (size_t)(m0 + (wave << 4) + r_in) * K + scolb;
  const signed char* gA1 = gA0 + ((size_t)K << 6);   // +64 rows
  const signed char* gB0 = Bw + (size_t)(n0 + (wave << 4) + r_in) * K + scolb;
  const signed char* gB1 = gB0 + ((size_t)K << 6);
  const int ldsoff = (wave << 10) + (lane << 4);     // A-chunk dest in buf

  auto stage = [&](int buf) {
    char* b = smem + buf * 16384 + ldsoff;
    gload_lds16(gA0, b);
    gload_lds16(gA1, b + 4096);
    gload_lds16(gB0, b + 8192);
    gload_lds16(gB1, b + 12288);
    gA0 += 64; gA1 += 64; gB0 += 64; gB1 += 64;
  };

  const int lrow = lane & 15;
  const int koff = ((lane >> 4) << 4) ^ (((lrow >> 1) & 3) << 4);

  const int nt = K >> 6;  // 16 for K=1024

  stage(0);

  for (int t = 0; t < nt; ++t) {
    const int buf = t & 1;
    asm volatile("s_waitcnt vmcnt(0)" ::: "memory");  // stage(t) landed
    __builtin_amdgcn_s_barrier();
    __builtin_amdgcn_sched_barrier(0);  // keep ds_reads below the barrier

    i32x4 af[4], bg[4];
    const char* base = smem + buf * 16384;
#pragma unroll
    for (int i = 0; i < 4; ++i) {
      af[i] = *(const i32x4*)(base + (wm + (i << 4) + lrow) * 64 + koff);
      bg[i] = *(const i32x4*)(base + 8192 + (wn + (i << 4) + lrow) * 64 + koff);
    }

    if (t + 1 < nt) stage(buf ^ 1);  // target's readers done before barrier(t)

    // compiler emits counted lgkmcnt per MFMA dep
#pragma unroll
    for (int i = 0; i < 4; ++i)
#pragma unroll
      for (int j = 0; j < 4; ++j)
        acc[i][j] =
            __builtin_amdgcn_mfma_i32_16x16x64_i8(af[i], bg[j], acc[i][j], 0, 0, 0);
  }

  // epilogue: C/D layout col=lane&15, row=(lane>>4)*4+reg
  const int col0 = n0 + wn + lrow;
  const int rowb = m0 + wm + ((lane >> 4) << 2);
  float sb[4], bi[4];
#pragma unroll
  for (int j = 0; j < 4; ++j) {
    sb[j] = sB[col0 + (j << 4)];
    if (EPI == 0) bi[j] = bias[col0 + (j << 4)];
  }
#pragma unroll
  for (int i = 0; i < 4; ++i)
#pragma unroll
    for (int r = 0; r < 4; ++r) {
      const int row = rowb + (i << 4) + r;
      const float sa = (EPI == 1) ? sA[row] : (1.0f / 127.0f);
#pragma unroll
      for (int j = 0; j < 4; ++j) {
        const size_t idx = (size_t)row * N + (col0 + (j << 4));
        const float v = (float)acc[i][j][r] * (sa * sb[j]);
        if (EPI == 1) {
          ((bf16*)C)[idx] = (bf16)(1.0f / (1.0f + __expf(-v)));
        } else {
          ((float*)C)[idx] = v + bi[j];
        }
      }
    }
}

// ---------------------------------------------------------------------------
// Windowed Hamming attention.  One thread per (b,s,h).  Gate is folded into
// the output GEMM (W2 = Wo .* (emb1-emb0), bias = Wo @ emb0), so this emits
// raw o in [0,1] quantized to i8 with fixed scale 127.
// ---------------------------------------------------------------------------
__global__ __launch_bounds__(256) void rosa_attn(
    const bf16* __restrict__ qkv, signed char* __restrict__ Oq) {
  const int t = blockIdx.x * 256 + threadIdx.x;
  const int row = t >> 7;
  const int h = t & 127;
  const int sp = row & 4095;

  const bf16* qptr = qkv + (size_t)row * 3072 + h * 8;
  bf16x8 qv = *(const bf16x8*)qptr;
  float qb[8], qsum = 0.f;
#pragma unroll
  for (int c = 0; c < 8; ++c) {
    qb[c] = (float)qv[c];
    qsum += qb[c];
  }

  float oacc[8] = {};
  float wsum = 0.f;
  const int wmax = (sp + 1 < 8) ? (sp + 1) : 8;
  const float scale = 0.35355339059327373f;

  for (int d = 0; d < wmax; ++d) {
    const bf16* base = qkv + (size_t)(row - d) * 3072 + h * 8;
    bf16x8 kv = *(const bf16x8*)(base + 1024);
    bf16x8 vv = *(const bf16x8*)(base + 2048);
    float dot = 0.f, ksum = 0.f;
#pragma unroll
    for (int c = 0; c < 8; ++c) {
      const float kb = (float)kv[c];
      dot += qb[c] * kb;
      ksum += kb;
    }
    const float score = (8.0f + 2.0f * dot - qsum - ksum) * scale;
    const float w = __expf(score);
    wsum += w;
#pragma unroll
    for (int c = 0; c < 8; ++c) oacc[c] += w * (float)vv[c];
  }

  const float inv = 127.0f / wsum;
  scx8 outv;
#pragma unroll
  for (int c = 0; c < 8; ++c)
    outv[c] = (signed char)(int)(oacc[c] * inv + 0.5f);  // o in [0,1]
  *(scx8*)(Oq + (size_t)row * 1024 + h * 8) = outv;
}

// ---------------------------------------------------------------------------
// Per-row i8 quantization.  One block (256 thr) per 1024-elem row.
// ---------------------------------------------------------------------------
__global__ __launch_bounds__(256) void quant_all(
    const float* __restrict__ X, const float* __restrict__ Wq,
    const float* __restrict__ Wk, const float* __restrict__ Wv,
    const float* __restrict__ Wo, const float* __restrict__ emb0,
    const float* __restrict__ emb1, signed char* __restrict__ Xq,
    signed char* __restrict__ Wqkvq, signed char* __restrict__ W2q,
    float* __restrict__ sx, float* __restrict__ sw, float* __restrict__ sw2,
    float* __restrict__ bias) {
  __shared__ float redm[4], reds[4];
  const int b = blockIdx.x, tid = threadIdx.x;
  const float* srow;
  signed char* drow;
  float* sc;
  bool isW2 = false;
  int w2r = 0;
  if (b < 8192) {
    srow = X + (size_t)b * 1024; drow = Xq + (size_t)b * 1024; sc = sx + b;
  } else if (b < 11264) {
    const int r = b - 8192;
    const float* w = (r < 1024) ? Wq : (r < 2048 ? Wk : Wv);
    srow = w + (size_t)(r & 1023) * 1024;
    drow = Wqkvq + (size_t)r * 1024; sc = sw + r;
  } else {
    const int r = b - 11264; w2r = r;
    srow = Wo + (size_t)r * 1024; drow = W2q + (size_t)r * 1024; sc = sw2 + r;
    isW2 = true;
  }
  float4 v = ((const float4*)srow)[tid];
  float bsum = 0.f;
  if (isW2) {
    const float4 e1 = ((const float4*)emb1)[tid];
    const float4 e0 = ((const float4*)emb0)[tid];
    bsum = v.x * e0.x + v.y * e0.y + v.z * e0.z + v.w * e0.w;
    v.x *= (e1.x - e0.x); v.y *= (e1.y - e0.y);
    v.z *= (e1.z - e0.z); v.w *= (e1.w - e0.w);
  }
  float m = fmaxf(fmaxf(fabsf(v.x), fabsf(v.y)), fmaxf(fabsf(v.z), fabsf(v.w)));
#pragma unroll
  for (int off = 32; off; off >>= 1) m = fmaxf(m, __shfl_xor(m, off));
#pragma unroll
  for (int off = 32; off; off >>= 1) bsum += __shfl_xor(bsum, off);
  if ((tid & 63) == 0) { redm[tid >> 6] = m; reds[tid >> 6] = bsum; }
  __syncthreads();
  const float mx = fmaxf(fmaxf(redm[0], redm[1]), fmaxf(redm[2], redm[3]));
  const float inv = (mx > 0.f) ? 127.f / mx : 0.f;
  const int q0 = __float2int_rn(v.x * inv) & 255;
  const int q1 = __float2int_rn(v.y * inv) & 255;
  const int q2 = __float2int_rn(v.z * inv) & 255;
  const int q3 = __float2int_rn(v.w * inv) & 255;
  ((int*)drow)[tid] = q0 | (q1 << 8) | (q2 << 16) | (q3 << 24);
  if (tid == 0) {
    *sc = (mx > 0.f) ? mx / 127.f : 0.f;
    if (isW2) bias[w2r] = reds[0] + reds[1] + reds[2] + reds[3];
  }
}

// ---------------------------------------------------------------------------
extern "C" void kernel_launch(void* const* d_in, const int* in_sizes, int n_in,
                              void* d_out, int out_size, void* d_ws,
                              size_t ws_size, hipStream_t stream) {
  const float* X = (const float*)d_in[0];
  const float* Wq = (const float*)d_in[1];
  const float* Wk = (const float*)d_in[2];
  const float* Wv = (const float*)d_in[3];
  const float* Wo = (const float*)d_in[4];
  const float* emb0 = (const float*)d_in[5];
  const float* emb1 = (const float*)d_in[6];

  char* ws = (char*)d_ws;
  signed char* Xq    = (signed char*)(ws + 0);         // 8192*1024  (8 MB)
  signed char* Wqkvq = (signed char*)(ws + 8388608);   // 3072*1024  (3 MB)
  signed char* W2q   = (signed char*)(ws + 11534336);  // 1024*1024  (1 MB)
  float* sx   = (float*)(ws + 12582912);               // 8192 f32
  float* sw   = (float*)(ws + 12615680);               // 3072 f32
  float* sw2  = (float*)(ws + 12627968);               // 1024 f32
  float* bias = (float*)(ws + 12632064);               // 1024 f32
  bf16* QKVb  = (bf16*)(ws + 16777216);                // 8192*3072 bf16 (48 MB)
  signed char* Oq = (signed char*)(ws + 67108864);     // 8192*1024  (8 MB)
  float* out = (float*)d_out;

  // per-row i8 quantization of X, Wq|Wk|Wv, W2 (gate folded) + bias GEMV
  quant_all<<<12288, 256, 0, stream>>>(X, Wq, Wk, Wv, Wo, emb0, emb1, Xq,
                                       Wqkvq, W2q, sx, sw, sw2, bias);

  // fused QKV projection (i8 MFMA) + sigmoid -> bf16 (M=8192,N=3072,K=1024)
  gemm_i8<1><<<1536, 256, 0, stream>>>(Xq, Wqkvq, sx, sw, nullptr, QKVb, 8192,
                                       3072, 1024);

  // windowed attention -> raw o as i8 (scale 127)
  rosa_attn<<<4096, 256, 0, stream>>>(QKVb, Oq);

  // output projection (i8 MFMA) + bias -> f32 (M=8192,N=1024,K=1024)
  gemm_i8<0><<<512, 256, 0, stream>>>(Oq, W2q, nullptr, sw2, bias, out, 8192,
                                      1024, 1024);
}

// Round 13
// 98.849 us; speedup vs baseline: 2.2683x; 1.0352x over previous
//
#include <hip/hip_runtime.h>
#include <hip/hip_bf16.h>

typedef __bf16 bf16;
typedef __bf16 bf16x8 __attribute__((ext_vector_type(8)));
typedef int i32x4 __attribute__((ext_vector_type(4)));
typedef signed char scx8 __attribute__((ext_vector_type(8)));

__device__ __forceinline__ void gload_lds16(const void* g, void* l) {
  __builtin_amdgcn_global_load_lds(
      (const __attribute__((address_space(1))) void*)g,
      (__attribute__((address_space(3))) void*)l, 16, 0, 0);
}

// ---------------------------------------------------------------------------
// QKV i8 GEMM (r10 config — best measured 57.5us): 128x128 tile, BK=64B,
// 256 thr = 4 waves (2x2), 4x4 mfma_i32_16x16x64_i8.  Triple-buffered LDS
// (3x16KB), (256,3), depth-2 staging, counted vmcnt(4), hoisted pointers,
// 0-conflict XOR swizzle.  Epilogue: sigmoid((sA[m]*sB[n])*acc) -> bf16.
// ---------------------------------------------------------------------------
__global__ __launch_bounds__(256, 3) void gemm_qkv(
    const signed char* __restrict__ A, const signed char* __restrict__ Bw,
    const float* __restrict__ sA, const float* __restrict__ sB,
    bf16* __restrict__ C, int M, int N, int K) {
  __shared__ __align__(16) char smem[49152];
  const int tid = threadIdx.x;
  const int lane = tid & 63;
  const int wave = tid >> 6;

  const int nb = N >> 7;
  const int nwg = gridDim.x;
  const int q8 = nwg >> 3;
  const int tile = ((int)blockIdx.x & 7) * q8 + ((int)blockIdx.x >> 3);
  const int m0 = (tile / nb) << 7;
  const int n0 = (tile % nb) << 7;

  const int wm = (wave >> 1) << 6;
  const int wn = (wave & 1) << 6;

  i32x4 acc[4][4] = {};

  const int r_in = lane >> 2;
  const int swz = ((lane >> 3) & 3) << 4;
  const int scolb = ((lane & 3) << 4) ^ swz;
  const signed char* gA0 = A + (size_t)(m0 + (wave << 4) + r_in) * K + scolb;
  const signed char* gA1 = gA0 + ((size_t)K << 6);
  const signed char* gB0 = Bw + (size_t)(n0 + (wave << 4) + r_in) * K + scolb;
  const signed char* gB1 = gB0 + ((size_t)K << 6);
  const int ldsoff = (wave << 10) + (lane << 4);

  auto stage = [&](int buf) {
    char* b = smem + buf * 16384 + ldsoff;
    gload_lds16(gA0, b);
    gload_lds16(gA1, b + 4096);
    gload_lds16(gB0, b + 8192);
    gload_lds16(gB1, b + 12288);
    gA0 += 64; gA1 += 64; gB0 += 64; gB1 += 64;
  };

  const int lrow = lane & 15;
  const int koff = ((lane >> 4) << 4) ^ (((lrow >> 1) & 3) << 4);

  const int nt = K >> 6;  // 16

  stage(0);
  stage(1);

  int buf = 0, pb = 2;
  for (int t = 0; t < nt; ++t) {
    if (t == nt - 1) {
      asm volatile("s_waitcnt vmcnt(0)" ::: "memory");
    } else {
      asm volatile("s_waitcnt vmcnt(4)" ::: "memory");
    }
    __builtin_amdgcn_s_barrier();
    __builtin_amdgcn_sched_barrier(0);

    i32x4 af[4], bg[4];
    const char* base = smem + buf * 16384;
#pragma unroll
    for (int i = 0; i < 4; ++i) {
      af[i] = *(const i32x4*)(base + (wm + (i << 4) + lrow) * 64 + koff);
      bg[i] = *(const i32x4*)(base + 8192 + (wn + (i << 4) + lrow) * 64 + koff);
    }

    if (t + 2 < nt) stage(pb);

#pragma unroll
    for (int i = 0; i < 4; ++i)
#pragma unroll
      for (int j = 0; j < 4; ++j)
        acc[i][j] =
            __builtin_amdgcn_mfma_i32_16x16x64_i8(af[i], bg[j], acc[i][j], 0, 0, 0);

    if (++buf == 3) buf = 0;
    if (++pb == 3) pb = 0;
  }

  const int col0 = n0 + wn + lrow;
  const int rowb = m0 + wm + ((lane >> 4) << 2);
  float sb[4];
#pragma unroll
  for (int j = 0; j < 4; ++j) sb[j] = sB[col0 + (j << 4)];
#pragma unroll
  for (int i = 0; i < 4; ++i)
#pragma unroll
    for (int r = 0; r < 4; ++r) {
      const int row = rowb + (i << 4) + r;
      const float sa = sA[row];
#pragma unroll
      for (int j = 0; j < 4; ++j) {
        const size_t idx = (size_t)row * N + (col0 + (j << 4));
        const float v = (float)acc[i][j][r] * (sa * sb[j]);
        C[idx] = (bf16)(1.0f / (1.0f + __expf(-v)));
      }
    }
}

// ---------------------------------------------------------------------------
// Output i8 GEMM: 64x128 tile (r13: doubles block-parallelism vs 128^2 —
// 1024 blocks = 4/CU in the latency-bound regime).  BK=64B, 4 waves (2x2),
// wave tile 32x64 = 2x4 frags.  Triple-buffered LDS (3 x 12KB), counted
// vmcnt(3), same swizzle.  Epilogue: (sB[n]/127)*acc + bias[n] -> f32.
// ---------------------------------------------------------------------------
__global__ __launch_bounds__(256, 4) void gemm_out(
    const signed char* __restrict__ A, const signed char* __restrict__ Bw,
    const float* __restrict__ sB, const float* __restrict__ bias,
    float* __restrict__ C, int M, int N, int K) {
  __shared__ __align__(16) char smem[36864];  // 3 x 12KB (A 4KB + B 8KB)
  const int tid = threadIdx.x;
  const int lane = tid & 63;
  const int wave = tid >> 6;

  const int nb = N >> 7;  // 8
  const int nwg = gridDim.x;
  const int q8 = nwg >> 3;
  const int tile = ((int)blockIdx.x & 7) * q8 + ((int)blockIdx.x >> 3);
  const int m0 = (tile / nb) << 6;
  const int n0 = (tile % nb) << 7;

  const int wm = (wave >> 1) << 5;  // 0/32
  const int wn = (wave & 1) << 6;   // 0/64

  i32x4 acc[2][4] = {};

  const int r_in = lane >> 2;
  const int swz = ((lane >> 3) & 3) << 4;
  const int scolb = ((lane & 3) << 4) ^ swz;
  // chunks: wave (A, 64 rows), wave+4 (B rows 0-63), wave+8 (B rows 64-127)
  const signed char* gA0 = A + (size_t)(m0 + (wave << 4) + r_in) * K + scolb;
  const signed char* gB0 = Bw + (size_t)(n0 + (wave << 4) + r_in) * K + scolb;
  const signed char* gB1 = gB0 + ((size_t)K << 6);
  const int ldsoff = (wave << 10) + (lane << 4);

  auto stage = [&](int buf) {
    char* b = smem + buf * 12288 + ldsoff;
    gload_lds16(gA0, b);
    gload_lds16(gB0, b + 4096);
    gload_lds16(gB1, b + 8192);
    gA0 += 64; gB0 += 64; gB1 += 64;
  };

  const int lrow = lane & 15;
  const int koff = ((lane >> 4) << 4) ^ (((lrow >> 1) & 3) << 4);

  const int nt = K >> 6;  // 16

  stage(0);
  stage(1);

  int buf = 0, pb = 2;
  for (int t = 0; t < nt; ++t) {
    if (t == nt - 1) {
      asm volatile("s_waitcnt vmcnt(0)" ::: "memory");
    } else {
      asm volatile("s_waitcnt vmcnt(3)" ::: "memory");
    }
    __builtin_amdgcn_s_barrier();
    __builtin_amdgcn_sched_barrier(0);

    i32x4 af[2], bg[4];
    const char* base = smem + buf * 12288;
#pragma unroll
    for (int i = 0; i < 2; ++i)
      af[i] = *(const i32x4*)(base + (wm + (i << 4) + lrow) * 64 + koff);
#pragma unroll
    for (int j = 0; j < 4; ++j)
      bg[j] = *(const i32x4*)(base + 4096 + (wn + (j << 4) + lrow) * 64 + koff);

    if (t + 2 < nt) stage(pb);

#pragma unroll
    for (int i = 0; i < 2; ++i)
#pragma unroll
      for (int j = 0; j < 4; ++j)
        acc[i][j] =
            __builtin_amdgcn_mfma_i32_16x16x64_i8(af[i], bg[j], acc[i][j], 0, 0, 0);

    if (++buf == 3) buf = 0;
    if (++pb == 3) pb = 0;
  }

  const int col0 = n0 + wn + lrow;
  const int rowb = m0 + wm + ((lane >> 4) << 2);
  float sb[4], bi[4];
#pragma unroll
  for (int j = 0; j < 4; ++j) {
    sb[j] = sB[col0 + (j << 4)] * (1.0f / 127.0f);
    bi[j] = bias[col0 + (j << 4)];
  }
#pragma unroll
  for (int i = 0; i < 2; ++i)
#pragma unroll
    for (int r = 0; r < 4; ++r) {
      const int row = rowb + (i << 4) + r;
#pragma unroll
      for (int j = 0; j < 4; ++j) {
        const size_t idx = (size_t)row * N + (col0 + (j << 4));
        C[idx] = (float)acc[i][j][r] * sb[j] + bi[j];
      }
    }
}

// ---------------------------------------------------------------------------
// Windowed Hamming attention.  One thread per (b,s,h).  Gate folded into the
// output GEMM (W2 = Wo .* (emb1-emb0), bias = Wo @ emb0); emits raw o in
// [0,1] quantized to i8 with fixed scale 127.
// ---------------------------------------------------------------------------
__global__ __launch_bounds__(256) void rosa_attn(
    const bf16* __restrict__ qkv, signed char* __restrict__ Oq) {
  const int t = blockIdx.x * 256 + threadIdx.x;
  const int row = t >> 7;
  const int h = t & 127;
  const int sp = row & 4095;

  const bf16* qptr = qkv + (size_t)row * 3072 + h * 8;
  bf16x8 qv = *(const bf16x8*)qptr;
  float qb[8], qsum = 0.f;
#pragma unroll
  for (int c = 0; c < 8; ++c) {
    qb[c] = (float)qv[c];
    qsum += qb[c];
  }

  float oacc[8] = {};
  float wsum = 0.f;
  const int wmax = (sp + 1 < 8) ? (sp + 1) : 8;
  const float scale = 0.35355339059327373f;

  for (int d = 0; d < wmax; ++d) {
    const bf16* base = qkv + (size_t)(row - d) * 3072 + h * 8;
    bf16x8 kv = *(const bf16x8*)(base + 1024);
    bf16x8 vv = *(const bf16x8*)(base + 2048);
    float dot = 0.f, ksum = 0.f;
#pragma unroll
    for (int c = 0; c < 8; ++c) {
      const float kb = (float)kv[c];
      dot += qb[c] * kb;
      ksum += kb;
    }
    const float score = (8.0f + 2.0f * dot - qsum - ksum) * scale;
    const float w = __expf(score);
    wsum += w;
#pragma unroll
    for (int c = 0; c < 8; ++c) oacc[c] += w * (float)vv[c];
  }

  const float inv = 127.0f / wsum;
  scx8 outv;
#pragma unroll
  for (int c = 0; c < 8; ++c)
    outv[c] = (signed char)(int)(oacc[c] * inv + 0.5f);
  *(scx8*)(Oq + (size_t)row * 1024 + h * 8) = outv;
}

// ---------------------------------------------------------------------------
// Per-row i8 quantization, wave-per-row (r13: no __syncthreads, 4 float4 per
// lane).  3072 blocks x 4 waves = 12288 rows.
// rows [0,8192): X -> Xq,sx | [8192,11264): Wq/Wk/Wv -> Wqkvq,sw |
// [11264,12288): W2 = Wo.*(emb1-emb0) -> W2q,sw2 + bias = Wo@emb0.
// ---------------------------------------------------------------------------
__global__ __launch_bounds__(256) void quant_all(
    const float* __restrict__ X, const float* __restrict__ Wq,
    const float* __restrict__ Wk, const float* __restrict__ Wv,
    const float* __restrict__ Wo, const float* __restrict__ emb0,
    const float* __restrict__ emb1, signed char* __restrict__ Xq,
    signed char* __restrict__ Wqkvq, signed char* __restrict__ W2q,
    float* __restrict__ sx, float* __restrict__ sw, float* __restrict__ sw2,
    float* __restrict__ bias) {
  const int wrow = (blockIdx.x << 2) + ((threadIdx.x) >> 6);  // global row
  const int lane = threadIdx.x & 63;
  const float* srow;
  signed char* drow;
  float* sc;
  bool isW2 = false;
  int w2r = 0;
  if (wrow < 8192) {
    srow = X + (size_t)wrow * 1024; drow = Xq + (size_t)wrow * 1024;
    sc = sx + wrow;
  } else if (wrow < 11264) {
    const int r = wrow - 8192;
    const float* w = (r < 1024) ? Wq : (r < 2048 ? Wk : Wv);
    srow = w + (size_t)(r & 1023) * 1024;
    drow = Wqkvq + (size_t)r * 1024; sc = sw + r;
  } else {
    const int r = wrow - 11264; w2r = r;
    srow = Wo + (size_t)r * 1024; drow = W2q + (size_t)r * 1024; sc = sw2 + r;
    isW2 = true;
  }
  float4 v[4];
  float bsum = 0.f, m = 0.f;
#pragma unroll
  for (int p = 0; p < 4; ++p) {
    v[p] = ((const float4*)srow)[lane + (p << 6)];
    if (isW2) {
      const float4 e1 = ((const float4*)emb1)[lane + (p << 6)];
      const float4 e0 = ((const float4*)emb0)[lane + (p << 6)];
      bsum += v[p].x * e0.x + v[p].y * e0.y + v[p].z * e0.z + v[p].w * e0.w;
      v[p].x *= (e1.x - e0.x); v[p].y *= (e1.y - e0.y);
      v[p].z *= (e1.z - e0.z); v[p].w *= (e1.w - e0.w);
    }
    m = fmaxf(m, fmaxf(fmaxf(fabsf(v[p].x), fabsf(v[p].y)),
                       fmaxf(fabsf(v[p].z), fabsf(v[p].w))));
  }
#pragma unroll
  for (int off = 32; off; off >>= 1) m = fmaxf(m, __shfl_xor(m, off));
  if (isW2) {
#pragma unroll
    for (int off = 32; off; off >>= 1) bsum += __shfl_xor(bsum, off);
  }
  const float inv = (m > 0.f) ? 127.f / m : 0.f;
#pragma unroll
  for (int p = 0; p < 4; ++p) {
    const int q0 = __float2int_rn(v[p].x * inv) & 255;
    const int q1 = __float2int_rn(v[p].y * inv) & 255;
    const int q2 = __float2int_rn(v[p].z * inv) & 255;
    const int q3 = __float2int_rn(v[p].w * inv) & 255;
    ((int*)drow)[lane + (p << 6)] = q0 | (q1 << 8) | (q2 << 16) | (q3 << 24);
  }
  if (lane == 0) {
    *sc = (m > 0.f) ? m / 127.f : 0.f;
    if (isW2) bias[w2r] = bsum;
  }
}

// ---------------------------------------------------------------------------
extern "C" void kernel_launch(void* const* d_in, const int* in_sizes, int n_in,
                              void* d_out, int out_size, void* d_ws,
                              size_t ws_size, hipStream_t stream) {
  const float* X = (const float*)d_in[0];
  const float* Wq = (const float*)d_in[1];
  const float* Wk = (const float*)d_in[2];
  const float* Wv = (const float*)d_in[3];
  const float* Wo = (const float*)d_in[4];
  const float* emb0 = (const float*)d_in[5];
  const float* emb1 = (const float*)d_in[6];

  char* ws = (char*)d_ws;
  signed char* Xq    = (signed char*)(ws + 0);         // 8192*1024  (8 MB)
  signed char* Wqkvq = (signed char*)(ws + 8388608);   // 3072*1024  (3 MB)
  signed char* W2q   = (signed char*)(ws + 11534336);  // 1024*1024  (1 MB)
  float* sx   = (float*)(ws + 12582912);               // 8192 f32
  float* sw   = (float*)(ws + 12615680);               // 3072 f32
  float* sw2  = (float*)(ws + 12627968);               // 1024 f32
  float* bias = (float*)(ws + 12632064);               // 1024 f32
  bf16* QKVb  = (bf16*)(ws + 16777216);                // 8192*3072 bf16 (48 MB)
  signed char* Oq = (signed char*)(ws + 67108864);     // 8192*1024  (8 MB)
  float* out = (float*)d_out;

  // per-row i8 quantization (wave-per-row)
  quant_all<<<3072, 256, 0, stream>>>(X, Wq, Wk, Wv, Wo, emb0, emb1, Xq,
                                      Wqkvq, W2q, sx, sw, sw2, bias);

  // fused QKV projection (i8 MFMA) + sigmoid -> bf16 (M=8192,N=3072,K=1024)
  gemm_qkv<<<1536, 256, 0, stream>>>(Xq, Wqkvq, sx, sw, QKVb, 8192, 3072, 1024);

  // windowed attention -> raw o as i8 (scale 127)
  rosa_attn<<<4096, 256, 0, stream>>>(QKVb, Oq);

  // output projection (i8 MFMA) + bias -> f32 (M=8192,N=1024,K=1024)
  // 64x128 tiles: 128 * 8 = 1024 blocks (4/CU)
  gemm_out<<<1024, 256, 0, stream>>>(Oq, W2q, sw2, bias, out, 8192, 1024, 1024);
}

// Round 14
// 97.818 us; speedup vs baseline: 2.2922x; 1.0105x over previous
//
#include <hip/hip_runtime.h>
#include <hip/hip_bf16.h>

typedef __bf16 bf16;
typedef __bf16 bf16x8 __attribute__((ext_vector_type(8)));
typedef int i32x4 __attribute__((ext_vector_type(4)));
typedef signed char scx8 __attribute__((ext_vector_type(8)));

__device__ __forceinline__ void gload_lds16(const void* g, void* l) {
  __builtin_amdgcn_global_load_lds(
      (const __attribute__((address_space(1))) void*)g,
      (__attribute__((address_space(3))) void*)l, 16, 0, 0);
}

// ---------------------------------------------------------------------------
// QKV i8 GEMM: 128x128 tile, BK=64B, 4 waves (2x2), 4x4 mfma_i32_16x16x64_i8.
// Triple-buffered LDS (3x16KB), (256,3), depth-2 staging, counted vmcnt(4),
// 0-conflict XOR swizzle.  r14: K is a template constant and the 16-iter
// K-loop is FULLY UNROLLED -> ring indices/LDS offsets become immediates
// (r13 VALUBusy 31.6% was dominated by runtime ring/address arithmetic).
// Numerics identical to r10-r13 (absmax must stay 6.561e-4).
// Epilogue: sigmoid((sA[m]*sB[n])*acc) -> bf16.
// ---------------------------------------------------------------------------
template <int K>
__global__ __launch_bounds__(256, 3) void gemm_qkv(
    const signed char* __restrict__ A, const signed char* __restrict__ Bw,
    const float* __restrict__ sA, const float* __restrict__ sB,
    bf16* __restrict__ C, int M, int N) {
  __shared__ __align__(16) char smem[49152];
  const int tid = threadIdx.x;
  const int lane = tid & 63;
  const int wave = tid >> 6;

  const int nb = N >> 7;
  const int nwg = gridDim.x;
  const int q8 = nwg >> 3;
  const int tile = ((int)blockIdx.x & 7) * q8 + ((int)blockIdx.x >> 3);
  const int m0 = (tile / nb) << 7;
  const int n0 = (tile % nb) << 7;

  const int wm = (wave >> 1) << 6;
  const int wn = (wave & 1) << 6;

  i32x4 acc[4][4] = {};

  const int r_in = lane >> 2;
  const int swz = ((lane >> 3) & 3) << 4;
  const int scolb = ((lane & 3) << 4) ^ swz;
  const signed char* gA0 = A + (size_t)(m0 + (wave << 4) + r_in) * K + scolb;
  const signed char* gA1 = gA0 + ((size_t)K << 6);
  const signed char* gB0 = Bw + (size_t)(n0 + (wave << 4) + r_in) * K + scolb;
  const signed char* gB1 = gB0 + ((size_t)K << 6);
  const int ldsoff = (wave << 10) + (lane << 4);

  constexpr int NT = K >> 6;  // 16

  // stage(t) into buf t%3; global column offset = t*64 (compile-time)
  auto stage = [&](int t) {
    char* b = smem + (t % 3) * 16384 + ldsoff;
    const int ko = t << 6;
    gload_lds16(gA0 + ko, b);
    gload_lds16(gA1 + ko, b + 4096);
    gload_lds16(gB0 + ko, b + 8192);
    gload_lds16(gB1 + ko, b + 12288);
  };

  const int lrow = lane & 15;
  const int koff = ((lane >> 4) << 4) ^ (((lrow >> 1) & 3) << 4);
  const int aoff = (wm + lrow) * 64 + koff;
  const int boff = 8192 + (wn + lrow) * 64 + koff;

  stage(0);
  stage(1);

#pragma unroll
  for (int t = 0; t < NT; ++t) {
    if (t == NT - 1) {
      asm volatile("s_waitcnt vmcnt(0)" ::: "memory");
    } else {
      asm volatile("s_waitcnt vmcnt(4)" ::: "memory");
    }
    __builtin_amdgcn_s_barrier();
    __builtin_amdgcn_sched_barrier(0);

    i32x4 af[4], bg[4];
    const char* base = smem + (t % 3) * 16384;  // compile-time per unrolled t
#pragma unroll
    for (int i = 0; i < 4; ++i) {
      af[i] = *(const i32x4*)(base + aoff + (i << 10));
      bg[i] = *(const i32x4*)(base + boff + (i << 10));
    }

    if (t + 2 < NT) stage(t + 2);

#pragma unroll
    for (int i = 0; i < 4; ++i)
#pragma unroll
      for (int j = 0; j < 4; ++j)
        acc[i][j] =
            __builtin_amdgcn_mfma_i32_16x16x64_i8(af[i], bg[j], acc[i][j], 0, 0, 0);
  }

  const int col0 = n0 + wn + lrow;
  const int rowb = m0 + wm + ((lane >> 4) << 2);
  float sb[4];
#pragma unroll
  for (int j = 0; j < 4; ++j) sb[j] = sB[col0 + (j << 4)];
#pragma unroll
  for (int i = 0; i < 4; ++i)
#pragma unroll
    for (int r = 0; r < 4; ++r) {
      const int row = rowb + (i << 4) + r;
      const float sa = sA[row];
#pragma unroll
      for (int j = 0; j < 4; ++j) {
        const size_t idx = (size_t)row * N + (col0 + (j << 4));
        const float v = (float)acc[i][j][r] * (sa * sb[j]);
        C[idx] = (bf16)(1.0f / (1.0f + __expf(-v)));
      }
    }
}

// ---------------------------------------------------------------------------
// Output i8 GEMM: 64x128 tile, 4 waves (2x2), wave tile 32x64 (2x4 frags).
// Triple-buffered LDS (3x12KB), counted vmcnt(3), fully unrolled like QKV.
// Epilogue: (sB[n]/127)*acc + bias[n] -> f32.
// ---------------------------------------------------------------------------
template <int K>
__global__ __launch_bounds__(256, 4) void gemm_out(
    const signed char* __restrict__ A, const signed char* __restrict__ Bw,
    const float* __restrict__ sB, const float* __restrict__ bias,
    float* __restrict__ C, int M, int N) {
  __shared__ __align__(16) char smem[36864];
  const int tid = threadIdx.x;
  const int lane = tid & 63;
  const int wave = tid >> 6;

  const int nb = N >> 7;
  const int nwg = gridDim.x;
  const int q8 = nwg >> 3;
  const int tile = ((int)blockIdx.x & 7) * q8 + ((int)blockIdx.x >> 3);
  const int m0 = (tile / nb) << 6;
  const int n0 = (tile % nb) << 7;

  const int wm = (wave >> 1) << 5;
  const int wn = (wave & 1) << 6;

  i32x4 acc[2][4] = {};

  const int r_in = lane >> 2;
  const int swz = ((lane >> 3) & 3) << 4;
  const int scolb = ((lane & 3) << 4) ^ swz;
  const signed char* gA0 = A + (size_t)(m0 + (wave << 4) + r_in) * K + scolb;
  const signed char* gB0 = Bw + (size_t)(n0 + (wave << 4) + r_in) * K + scolb;
  const signed char* gB1 = gB0 + ((size_t)K << 6);
  const int ldsoff = (wave << 10) + (lane << 4);

  constexpr int NT = K >> 6;  // 16

  auto stage = [&](int t) {
    char* b = smem + (t % 3) * 12288 + ldsoff;
    const int ko = t << 6;
    gload_lds16(gA0 + ko, b);
    gload_lds16(gB0 + ko, b + 4096);
    gload_lds16(gB1 + ko, b + 8192);
  };

  const int lrow = lane & 15;
  const int koff = ((lane >> 4) << 4) ^ (((lrow >> 1) & 3) << 4);
  const int aoff = (wm + lrow) * 64 + koff;
  const int boff = 4096 + (wn + lrow) * 64 + koff;

  stage(0);
  stage(1);

#pragma unroll
  for (int t = 0; t < NT; ++t) {
    if (t == NT - 1) {
      asm volatile("s_waitcnt vmcnt(0)" ::: "memory");
    } else {
      asm volatile("s_waitcnt vmcnt(3)" ::: "memory");
    }
    __builtin_amdgcn_s_barrier();
    __builtin_amdgcn_sched_barrier(0);

    i32x4 af[2], bg[4];
    const char* base = smem + (t % 3) * 12288;
#pragma unroll
    for (int i = 0; i < 2; ++i)
      af[i] = *(const i32x4*)(base + aoff + (i << 10));
#pragma unroll
    for (int j = 0; j < 4; ++j)
      bg[j] = *(const i32x4*)(base + boff + (j << 10));

    if (t + 2 < NT) stage(t + 2);

#pragma unroll
    for (int i = 0; i < 2; ++i)
#pragma unroll
      for (int j = 0; j < 4; ++j)
        acc[i][j] =
            __builtin_amdgcn_mfma_i32_16x16x64_i8(af[i], bg[j], acc[i][j], 0, 0, 0);
  }

  const int col0 = n0 + wn + lrow;
  const int rowb = m0 + wm + ((lane >> 4) << 2);
  float sb[4], bi[4];
#pragma unroll
  for (int j = 0; j < 4; ++j) {
    sb[j] = sB[col0 + (j << 4)] * (1.0f / 127.0f);
    bi[j] = bias[col0 + (j << 4)];
  }
#pragma unroll
  for (int i = 0; i < 2; ++i)
#pragma unroll
    for (int r = 0; r < 4; ++r) {
      const int row = rowb + (i << 4) + r;
#pragma unroll
      for (int j = 0; j < 4; ++j) {
        const size_t idx = (size_t)row * N + (col0 + (j << 4));
        C[idx] = (float)acc[i][j][r] * sb[j] + bi[j];
      }
    }
}

// ---------------------------------------------------------------------------
// Windowed Hamming attention.  One thread per (b,s,h).  Gate folded into the
// output GEMM; emits raw o in [0,1] quantized to i8 with fixed scale 127.
// ---------------------------------------------------------------------------
__global__ __launch_bounds__(256) void rosa_attn(
    const bf16* __restrict__ qkv, signed char* __restrict__ Oq) {
  const int t = blockIdx.x * 256 + threadIdx.x;
  const int row = t >> 7;
  const int h = t & 127;
  const int sp = row & 4095;

  const bf16* qptr = qkv + (size_t)row * 3072 + h * 8;
  bf16x8 qv = *(const bf16x8*)qptr;
  float qb[8], qsum = 0.f;
#pragma unroll
  for (int c = 0; c < 8; ++c) {
    qb[c] = (float)qv[c];
    qsum += qb[c];
  }

  float oacc[8] = {};
  float wsum = 0.f;
  const int wmax = (sp + 1 < 8) ? (sp + 1) : 8;
  const float scale = 0.35355339059327373f;

  for (int d = 0; d < wmax; ++d) {
    const bf16* base = qkv + (size_t)(row - d) * 3072 + h * 8;
    bf16x8 kv = *(const bf16x8*)(base + 1024);
    bf16x8 vv = *(const bf16x8*)(base + 2048);
    float dot = 0.f, ksum = 0.f;
#pragma unroll
    for (int c = 0; c < 8; ++c) {
      const float kb = (float)kv[c];
      dot += qb[c] * kb;
      ksum += kb;
    }
    const float score = (8.0f + 2.0f * dot - qsum - ksum) * scale;
    const float w = __expf(score);
    wsum += w;
#pragma unroll
    for (int c = 0; c < 8; ++c) oacc[c] += w * (float)vv[c];
  }

  const float inv = 127.0f / wsum;
  scx8 outv;
#pragma unroll
  for (int c = 0; c < 8; ++c)
    outv[c] = (signed char)(int)(oacc[c] * inv + 0.5f);
  *(scx8*)(Oq + (size_t)row * 1024 + h * 8) = outv;
}

// ---------------------------------------------------------------------------
// Per-row i8 quantization, wave-per-row.  3072 blocks x 4 waves = 12288 rows.
// ---------------------------------------------------------------------------
__global__ __launch_bounds__(256) void quant_all(
    const float* __restrict__ X, const float* __restrict__ Wq,
    const float* __restrict__ Wk, const float* __restrict__ Wv,
    const float* __restrict__ Wo, const float* __restrict__ emb0,
    const float* __restrict__ emb1, signed char* __restrict__ Xq,
    signed char* __restrict__ Wqkvq, signed char* __restrict__ W2q,
    float* __restrict__ sx, float* __restrict__ sw, float* __restrict__ sw2,
    float* __restrict__ bias) {
  const int wrow = (blockIdx.x << 2) + ((threadIdx.x) >> 6);
  const int lane = threadIdx.x & 63;
  const float* srow;
  signed char* drow;
  float* sc;
  bool isW2 = false;
  int w2r = 0;
  if (wrow < 8192) {
    srow = X + (size_t)wrow * 1024; drow = Xq + (size_t)wrow * 1024;
    sc = sx + wrow;
  } else if (wrow < 11264) {
    const int r = wrow - 8192;
    const float* w = (r < 1024) ? Wq : (r < 2048 ? Wk : Wv);
    srow = w + (size_t)(r & 1023) * 1024;
    drow = Wqkvq + (size_t)r * 1024; sc = sw + r;
  } else {
    const int r = wrow - 11264; w2r = r;
    srow = Wo + (size_t)r * 1024; drow = W2q + (size_t)r * 1024; sc = sw2 + r;
    isW2 = true;
  }
  float4 v[4];
  float bsum = 0.f, m = 0.f;
#pragma unroll
  for (int p = 0; p < 4; ++p) {
    v[p] = ((const float4*)srow)[lane + (p << 6)];
    if (isW2) {
      const float4 e1 = ((const float4*)emb1)[lane + (p << 6)];
      const float4 e0 = ((const float4*)emb0)[lane + (p << 6)];
      bsum += v[p].x * e0.x + v[p].y * e0.y + v[p].z * e0.z + v[p].w * e0.w;
      v[p].x *= (e1.x - e0.x); v[p].y *= (e1.y - e0.y);
      v[p].z *= (e1.z - e0.z); v[p].w *= (e1.w - e0.w);
    }
    m = fmaxf(m, fmaxf(fmaxf(fabsf(v[p].x), fabsf(v[p].y)),
                       fmaxf(fabsf(v[p].z), fabsf(v[p].w))));
  }
#pragma unroll
  for (int off = 32; off; off >>= 1) m = fmaxf(m, __shfl_xor(m, off));
  if (isW2) {
#pragma unroll
    for (int off = 32; off; off >>= 1) bsum += __shfl_xor(bsum, off);
  }
  const float inv = (m > 0.f) ? 127.f / m : 0.f;
#pragma unroll
  for (int p = 0; p < 4; ++p) {
    const int q0 = __float2int_rn(v[p].x * inv) & 255;
    const int q1 = __float2int_rn(v[p].y * inv) & 255;
    const int q2 = __float2int_rn(v[p].z * inv) & 255;
    const int q3 = __float2int_rn(v[p].w * inv) & 255;
    ((int*)drow)[lane + (p << 6)] = q0 | (q1 << 8) | (q2 << 16) | (q3 << 24);
  }
  if (lane == 0) {
    *sc = (m > 0.f) ? m / 127.f : 0.f;
    if (isW2) bias[w2r] = bsum;
  }
}

// ---------------------------------------------------------------------------
extern "C" void kernel_launch(void* const* d_in, const int* in_sizes, int n_in,
                              void* d_out, int out_size, void* d_ws,
                              size_t ws_size, hipStream_t stream) {
  const float* X = (const float*)d_in[0];
  const float* Wq = (const float*)d_in[1];
  const float* Wk = (const float*)d_in[2];
  const float* Wv = (const float*)d_in[3];
  const float* Wo = (const float*)d_in[4];
  const float* emb0 = (const float*)d_in[5];
  const float* emb1 = (const float*)d_in[6];

  char* ws = (char*)d_ws;
  signed char* Xq    = (signed char*)(ws + 0);         // 8192*1024  (8 MB)
  signed char* Wqkvq = (signed char*)(ws + 8388608);   // 3072*1024  (3 MB)
  signed char* W2q   = (signed char*)(ws + 11534336);  // 1024*1024  (1 MB)
  float* sx   = (float*)(ws + 12582912);               // 8192 f32
  float* sw   = (float*)(ws + 12615680);               // 3072 f32
  float* sw2  = (float*)(ws + 12627968);               // 1024 f32
  float* bias = (float*)(ws + 12632064);               // 1024 f32
  bf16* QKVb  = (bf16*)(ws + 16777216);                // 8192*3072 bf16 (48 MB)
  signed char* Oq = (signed char*)(ws + 67108864);     // 8192*1024  (8 MB)
  float* out = (float*)d_out;

  // per-row i8 quantization (wave-per-row)
  quant_all<<<3072, 256, 0, stream>>>(X, Wq, Wk, Wv, Wo, emb0, emb1, Xq,
                                      Wqkvq, W2q, sx, sw, sw2, bias);

  // fused QKV projection (i8 MFMA) + sigmoid -> bf16 (M=8192,N=3072,K=1024)
  gemm_qkv<1024><<<1536, 256, 0, stream>>>(Xq, Wqkvq, sx, sw, QKVb, 8192, 3072);

  // windowed attention -> raw o as i8 (scale 127)
  rosa_attn<<<4096, 256, 0, stream>>>(QKVb, Oq);

  // output projection (i8 MFMA) + bias -> f32 (M=8192,N=1024,K=1024)
  gemm_out<1024><<<1024, 256, 0, stream>>>(Oq, W2q, sw2, bias, out, 8192, 1024);
}

// Round 15
// 88.864 us; speedup vs baseline: 2.5231x; 1.1008x over previous
//
#include <hip/hip_runtime.h>
#include <hip/hip_bf16.h>

typedef __bf16 bf16;
typedef __bf16 bf16x8 __attribute__((ext_vector_type(8)));
typedef int i32x4 __attribute__((ext_vector_type(4)));
typedef signed char scx8 __attribute__((ext_vector_type(8)));

__device__ __forceinline__ void gload_lds16(const void* g, void* l) {
  __builtin_amdgcn_global_load_lds(
      (const __attribute__((address_space(1))) void*)g,
      (__attribute__((address_space(3))) void*)l, 16, 0, 0);
}

// ---------------------------------------------------------------------------
// QKV i8 GEMM — exact r10 config (best measured 57.5us): 128x128 tile,
// BK=64B, 4 waves (2x2), 4x4 mfma_i32_16x16x64_i8.  Triple-buffered LDS
// (3x16KB), (256,3), depth-2 staging, counted vmcnt(4), hoisted pointers,
// 0-conflict XOR swizzle.  Epilogue: sigmoid((sA[m]*sB[n])*acc) -> bf16.
// ---------------------------------------------------------------------------
__global__ __launch_bounds__(256, 3) void gemm_qkv(
    const signed char* __restrict__ A, const signed char* __restrict__ Bw,
    const float* __restrict__ sA, const float* __restrict__ sB,
    bf16* __restrict__ C, int M, int N, int K) {
  __shared__ __align__(16) char smem[49152];
  const int tid = threadIdx.x;
  const int lane = tid & 63;
  const int wave = tid >> 6;

  const int nb = N >> 7;
  const int nwg = gridDim.x;
  const int q8 = nwg >> 3;
  const int tile = ((int)blockIdx.x & 7) * q8 + ((int)blockIdx.x >> 3);
  const int m0 = (tile / nb) << 7;
  const int n0 = (tile % nb) << 7;

  const int wm = (wave >> 1) << 6;
  const int wn = (wave & 1) << 6;

  i32x4 acc[4][4] = {};

  const int r_in = lane >> 2;
  const int swz = ((lane >> 3) & 3) << 4;
  const int scolb = ((lane & 3) << 4) ^ swz;
  const signed char* gA0 = A + (size_t)(m0 + (wave << 4) + r_in) * K + scolb;
  const signed char* gA1 = gA0 + ((size_t)K << 6);
  const signed char* gB0 = Bw + (size_t)(n0 + (wave << 4) + r_in) * K + scolb;
  const signed char* gB1 = gB0 + ((size_t)K << 6);
  const int ldsoff = (wave << 10) + (lane << 4);

  auto stage = [&](int buf) {
    char* b = smem + buf * 16384 + ldsoff;
    gload_lds16(gA0, b);
    gload_lds16(gA1, b + 4096);
    gload_lds16(gB0, b + 8192);
    gload_lds16(gB1, b + 12288);
    gA0 += 64; gA1 += 64; gB0 += 64; gB1 += 64;
  };

  const int lrow = lane & 15;
  const int koff = ((lane >> 4) << 4) ^ (((lrow >> 1) & 3) << 4);

  const int nt = K >> 6;  // 16

  stage(0);
  stage(1);

  int buf = 0, pb = 2;
  for (int t = 0; t < nt; ++t) {
    if (t == nt - 1) {
      asm volatile("s_waitcnt vmcnt(0)" ::: "memory");
    } else {
      asm volatile("s_waitcnt vmcnt(4)" ::: "memory");
    }
    __builtin_amdgcn_s_barrier();
    __builtin_amdgcn_sched_barrier(0);

    i32x4 af[4], bg[4];
    const char* base = smem + buf * 16384;
#pragma unroll
    for (int i = 0; i < 4; ++i) {
      af[i] = *(const i32x4*)(base + (wm + (i << 4) + lrow) * 64 + koff);
      bg[i] = *(const i32x4*)(base + 8192 + (wn + (i << 4) + lrow) * 64 + koff);
    }

    if (t + 2 < nt) stage(pb);

#pragma unroll
    for (int i = 0; i < 4; ++i)
#pragma unroll
      for (int j = 0; j < 4; ++j)
        acc[i][j] =
            __builtin_amdgcn_mfma_i32_16x16x64_i8(af[i], bg[j], acc[i][j], 0, 0, 0);

    if (++buf == 3) buf = 0;
    if (++pb == 3) pb = 0;
  }

  const int col0 = n0 + wn + lrow;
  const int rowb = m0 + wm + ((lane >> 4) << 2);
  float sb[4];
#pragma unroll
  for (int j = 0; j < 4; ++j) sb[j] = sB[col0 + (j << 4)];
#pragma unroll
  for (int i = 0; i < 4; ++i)
#pragma unroll
    for (int r = 0; r < 4; ++r) {
      const int row = rowb + (i << 4) + r;
      const float sa = sA[row];
#pragma unroll
      for (int j = 0; j < 4; ++j) {
        const size_t idx = (size_t)row * N + (col0 + (j << 4));
        const float v = (float)acc[i][j][r] * (sa * sb[j]);
        C[idx] = (bf16)(1.0f / (1.0f + __expf(-v)));
      }
    }
}

// ---------------------------------------------------------------------------
// Output i8 GEMM: 64x128 tile, 4 waves (2x2), wave tile 32x64 (2x4 frags).
// Triple-buffered LDS (3x12KB), counted vmcnt(3), fully unrolled (K templ).
// Epilogue: (sB[n]/127)*acc + bias[n] -> f32.
// ---------------------------------------------------------------------------
template <int K>
__global__ __launch_bounds__(256, 4) void gemm_out(
    const signed char* __restrict__ A, const signed char* __restrict__ Bw,
    const float* __restrict__ sB, const float* __restrict__ bias,
    float* __restrict__ C, int M, int N) {
  __shared__ __align__(16) char smem[36864];
  const int tid = threadIdx.x;
  const int lane = tid & 63;
  const int wave = tid >> 6;

  const int nb = N >> 7;
  const int nwg = gridDim.x;
  const int q8 = nwg >> 3;
  const int tile = ((int)blockIdx.x & 7) * q8 + ((int)blockIdx.x >> 3);
  const int m0 = (tile / nb) << 6;
  const int n0 = (tile % nb) << 7;

  const int wm = (wave >> 1) << 5;
  const int wn = (wave & 1) << 6;

  i32x4 acc[2][4] = {};

  const int r_in = lane >> 2;
  const int swz = ((lane >> 3) & 3) << 4;
  const int scolb = ((lane & 3) << 4) ^ swz;
  const signed char* gA0 = A + (size_t)(m0 + (wave << 4) + r_in) * K + scolb;
  const signed char* gB0 = Bw + (size_t)(n0 + (wave << 4) + r_in) * K + scolb;
  const signed char* gB1 = gB0 + ((size_t)K << 6);
  const int ldsoff = (wave << 10) + (lane << 4);

  constexpr int NT = K >> 6;  // 16

  auto stage = [&](int t) {
    char* b = smem + (t % 3) * 12288 + ldsoff;
    const int ko = t << 6;
    gload_lds16(gA0 + ko, b);
    gload_lds16(gB0 + ko, b + 4096);
    gload_lds16(gB1 + ko, b + 8192);
  };

  const int lrow = lane & 15;
  const int koff = ((lane >> 4) << 4) ^ (((lrow >> 1) & 3) << 4);
  const int aoff = (wm + lrow) * 64 + koff;
  const int boff = 4096 + (wn + lrow) * 64 + koff;

  stage(0);
  stage(1);

#pragma unroll
  for (int t = 0; t < NT; ++t) {
    if (t == NT - 1) {
      asm volatile("s_waitcnt vmcnt(0)" ::: "memory");
    } else {
      asm volatile("s_waitcnt vmcnt(3)" ::: "memory");
    }
    __builtin_amdgcn_s_barrier();
    __builtin_amdgcn_sched_barrier(0);

    i32x4 af[2], bg[4];
    const char* base = smem + (t % 3) * 12288;
#pragma unroll
    for (int i = 0; i < 2; ++i)
      af[i] = *(const i32x4*)(base + aoff + (i << 10));
#pragma unroll
    for (int j = 0; j < 4; ++j)
      bg[j] = *(const i32x4*)(base + boff + (j << 10));

    if (t + 2 < NT) stage(t + 2);

#pragma unroll
    for (int i = 0; i < 2; ++i)
#pragma unroll
      for (int j = 0; j < 4; ++j)
        acc[i][j] =
            __builtin_amdgcn_mfma_i32_16x16x64_i8(af[i], bg[j], acc[i][j], 0, 0, 0);
  }

  const int col0 = n0 + wn + lrow;
  const int rowb = m0 + wm + ((lane >> 4) << 2);
  float sb[4], bi[4];
#pragma unroll
  for (int j = 0; j < 4; ++j) {
    sb[j] = sB[col0 + (j << 4)] * (1.0f / 127.0f);
    bi[j] = bias[col0 + (j << 4)];
  }
#pragma unroll
  for (int i = 0; i < 2; ++i)
#pragma unroll
    for (int r = 0; r < 4; ++r) {
      const int row = rowb + (i << 4) + r;
#pragma unroll
      for (int j = 0; j < 4; ++j) {
        const size_t idx = (size_t)row * N + (col0 + (j << 4));
        C[idx] = (float)acc[i][j][r] * sb[j] + bi[j];
      }
    }
}

// ---------------------------------------------------------------------------
// Windowed Hamming attention, register-ring version (r15).
// 8 rows per thread, fixed head h: k/v/ksum for the last 8 rows live in a
// compile-time-indexed register ring (both loops unrolled -> no scratch,
// rule #20).  Each row's k/v read ONCE (was 8x re-read via window loop).
// Per-row math order identical to r9-r14 -> bit-identical Oq.
// Gate folded into output GEMM; emits o in [0,1] as i8, fixed scale 127.
// ---------------------------------------------------------------------------
__global__ __launch_bounds__(256) void rosa_attn(
    const bf16* __restrict__ qkv, signed char* __restrict__ Oq) {
  const int t = blockIdx.x * 256 + threadIdx.x;  // 131072 threads
  const int h = t & 127;
  const int rbase = (t >> 7) << 3;  // 8 rows per thread, 8-aligned
  const int hoff = h * 8;
  const float scale = 0.35355339059327373f;

  bf16x8 kr[8], vr[8];
  float ksum[8];

  // preload rows rbase-7..rbase-1 (all-or-none: rbase&4095==0 means none)
  if ((rbase & 4095) != 0) {
#pragma unroll
    for (int p = 1; p <= 7; ++p) {
      const int row = rbase - p;
      const int slot = (8 - p) & 7;  // (row)&7 since rbase&7==0
      const bf16* base = qkv + (size_t)row * 3072 + hoff;
      kr[slot] = *(const bf16x8*)(base + 1024);
      vr[slot] = *(const bf16x8*)(base + 2048);
      float s = 0.f;
#pragma unroll
      for (int c = 0; c < 8; ++c) s += (float)kr[slot][c];
      ksum[slot] = s;
    }
  }

#pragma unroll
  for (int rr = 0; rr < 8; ++rr) {
    const int row = rbase + rr;
    const int sp = row & 4095;
    const bf16* base = qkv + (size_t)row * 3072 + hoff;
    // load this row's q,k,v (k/v into ring slot rr)
    bf16x8 qv = *(const bf16x8*)base;
    kr[rr] = *(const bf16x8*)(base + 1024);
    vr[rr] = *(const bf16x8*)(base + 2048);
    float qb[8], qsum = 0.f, s = 0.f;
#pragma unroll
    for (int c = 0; c < 8; ++c) {
      qb[c] = (float)qv[c];
      qsum += qb[c];
      s += (float)kr[rr][c];
    }
    ksum[rr] = s;

    const int wmax = (sp + 1 < 8) ? (sp + 1) : 8;
    float oacc[8] = {};
    float wsum = 0.f;
#pragma unroll
    for (int d = 0; d < 8; ++d) {
      if (d < wmax) {  // wave-uniform
        const int slot = (rr - d) & 7;  // compile-time
        float dot = 0.f;
#pragma unroll
        for (int c = 0; c < 8; ++c) dot += qb[c] * (float)kr[slot][c];
        const float score = (8.0f + 2.0f * dot - qsum - ksum[slot]) * scale;
        const float w = __expf(score);
        wsum += w;
#pragma unroll
        for (int c = 0; c < 8; ++c) oacc[c] += w * (float)vr[slot][c];
      }
    }

    const float inv = 127.0f / wsum;
    scx8 outv;
#pragma unroll
    for (int c = 0; c < 8; ++c)
      outv[c] = (signed char)(int)(oacc[c] * inv + 0.5f);
    *(scx8*)(Oq + (size_t)row * 1024 + hoff) = outv;
  }
}

// ---------------------------------------------------------------------------
// Per-row i8 quantization, wave-per-row.  3072 blocks x 4 waves = 12288 rows.
// ---------------------------------------------------------------------------
__global__ __launch_bounds__(256) void quant_all(
    const float* __restrict__ X, const float* __restrict__ Wq,
    const float* __restrict__ Wk, const float* __restrict__ Wv,
    const float* __restrict__ Wo, const float* __restrict__ emb0,
    const float* __restrict__ emb1, signed char* __restrict__ Xq,
    signed char* __restrict__ Wqkvq, signed char* __restrict__ W2q,
    float* __restrict__ sx, float* __restrict__ sw, float* __restrict__ sw2,
    float* __restrict__ bias) {
  const int wrow = (blockIdx.x << 2) + ((threadIdx.x) >> 6);
  const int lane = threadIdx.x & 63;
  const float* srow;
  signed char* drow;
  float* sc;
  bool isW2 = false;
  int w2r = 0;
  if (wrow < 8192) {
    srow = X + (size_t)wrow * 1024; drow = Xq + (size_t)wrow * 1024;
    sc = sx + wrow;
  } else if (wrow < 11264) {
    const int r = wrow - 8192;
    const float* w = (r < 1024) ? Wq : (r < 2048 ? Wk : Wv);
    srow = w + (size_t)(r & 1023) * 1024;
    drow = Wqkvq + (size_t)r * 1024; sc = sw + r;
  } else {
    const int r = wrow - 11264; w2r = r;
    srow = Wo + (size_t)r * 1024; drow = W2q + (size_t)r * 1024; sc = sw2 + r;
    isW2 = true;
  }
  float4 v[4];
  float bsum = 0.f, m = 0.f;
#pragma unroll
  for (int p = 0; p < 4; ++p) {
    v[p] = ((const float4*)srow)[lane + (p << 6)];
    if (isW2) {
      const float4 e1 = ((const float4*)emb1)[lane + (p << 6)];
      const float4 e0 = ((const float4*)emb0)[lane + (p << 6)];
      bsum += v[p].x * e0.x + v[p].y * e0.y + v[p].z * e0.z + v[p].w * e0.w;
      v[p].x *= (e1.x - e0.x); v[p].y *= (e1.y - e0.y);
      v[p].z *= (e1.z - e0.z); v[p].w *= (e1.w - e0.w);
    }
    m = fmaxf(m, fmaxf(fmaxf(fabsf(v[p].x), fabsf(v[p].y)),
                       fmaxf(fabsf(v[p].z), fabsf(v[p].w))));
  }
#pragma unroll
  for (int off = 32; off; off >>= 1) m = fmaxf(m, __shfl_xor(m, off));
  if (isW2) {
#pragma unroll
    for (int off = 32; off; off >>= 1) bsum += __shfl_xor(bsum, off);
  }
  const float inv = (m > 0.f) ? 127.f / m : 0.f;
#pragma unroll
  for (int p = 0; p < 4; ++p) {
    const int q0 = __float2int_rn(v[p].x * inv) & 255;
    const int q1 = __float2int_rn(v[p].y * inv) & 255;
    const int q2 = __float2int_rn(v[p].z * inv) & 255;
    const int q3 = __float2int_rn(v[p].w * inv) & 255;
    ((int*)drow)[lane + (p << 6)] = q0 | (q1 << 8) | (q2 << 16) | (q3 << 24);
  }
  if (lane == 0) {
    *sc = (m > 0.f) ? m / 127.f : 0.f;
    if (isW2) bias[w2r] = bsum;
  }
}

// ---------------------------------------------------------------------------
extern "C" void kernel_launch(void* const* d_in, const int* in_sizes, int n_in,
                              void* d_out, int out_size, void* d_ws,
                              size_t ws_size, hipStream_t stream) {
  const float* X = (const float*)d_in[0];
  const float* Wq = (const float*)d_in[1];
  const float* Wk = (const float*)d_in[2];
  const float* Wv = (const float*)d_in[3];
  const float* Wo = (const float*)d_in[4];
  const float* emb0 = (const float*)d_in[5];
  const float* emb1 = (const float*)d_in[6];

  char* ws = (char*)d_ws;
  signed char* Xq    = (signed char*)(ws + 0);         // 8192*1024  (8 MB)
  signed char* Wqkvq = (signed char*)(ws + 8388608);   // 3072*1024  (3 MB)
  signed char* W2q   = (signed char*)(ws + 11534336);  // 1024*1024  (1 MB)
  float* sx   = (float*)(ws + 12582912);               // 8192 f32
  float* sw   = (float*)(ws + 12615680);               // 3072 f32
  float* sw2  = (float*)(ws + 12627968);               // 1024 f32
  float* bias = (float*)(ws + 12632064);               // 1024 f32
  bf16* QKVb  = (bf16*)(ws + 16777216);                // 8192*3072 bf16 (48 MB)
  signed char* Oq = (signed char*)(ws + 67108864);     // 8192*1024  (8 MB)
  float* out = (float*)d_out;

  // per-row i8 quantization (wave-per-row)
  quant_all<<<3072, 256, 0, stream>>>(X, Wq, Wk, Wv, Wo, emb0, emb1, Xq,
                                      Wqkvq, W2q, sx, sw, sw2, bias);

  // fused QKV projection (i8 MFMA) + sigmoid -> bf16 (M=8192,N=3072,K=1024)
  gemm_qkv<<<1536, 256, 0, stream>>>(Xq, Wqkvq, sx, sw, QKVb, 8192, 3072, 1024);

  // windowed attention (register-ring) -> raw o as i8 (scale 127)
  rosa_attn<<<512, 256, 0, stream>>>(QKVb, Oq);

  // output projection (i8 MFMA) + bias -> f32 (M=8192,N=1024,K=1024)
  gemm_out<1024><<<1024, 256, 0, stream>>>(Oq, W2q, sw2, bias, out, 8192, 1024);
}